// Round 1
// baseline (575.557 us; speedup 1.0000x reference)
//
#include <hip/hip_runtime.h>
#include <hip/hip_bf16.h>
#include <stdint.h>

#define S_LEN 4096
#define EMB   2048
#define KVD   512
#define HD    128
#define NH    16

typedef __attribute__((ext_vector_type(8))) short short8;
typedef __attribute__((ext_vector_type(4))) float f32x4;

#define AS1 __attribute__((address_space(1)))
#define AS3 __attribute__((address_space(3)))

__device__ __forceinline__ void gl2lds16(const void* g, void* l) {
  __builtin_amdgcn_global_load_lds((AS1 void*)g, (AS3 void*)l, 16, 0, 0);
}

__device__ __forceinline__ unsigned short f2bu(float f) {
  __hip_bfloat16 h = __float2bfloat16(f);
  unsigned short u;
  __builtin_memcpy(&u, &h, 2);
  return u;
}

// ---------------- fp32 -> bf16 convert (vectorized) ----------------
__global__ void cvt_f32_bf16(const float* __restrict__ in, __hip_bfloat16* __restrict__ out, int n) {
  int i = blockIdx.x * blockDim.x + threadIdx.x;
  int stride = gridDim.x * blockDim.x;
  for (int idx = i * 4; idx < n; idx += stride * 4) {
    float4 f = *(const float4*)(in + idx);
    ushort4 u4 = make_ushort4(f2bu(f.x), f2bu(f.y), f2bu(f.z), f2bu(f.w));
    *reinterpret_cast<ushort4*>(out + idx) = u4;
  }
}

// ---------------- transpose fp32 [K][N] -> bf16 [N][K] ----------------
__global__ void transpose_f32_bf16(const float* __restrict__ W, __hip_bfloat16* __restrict__ WT,
                                   int K, int N) {
  __shared__ float t[32][33];
  int tx = threadIdx.x & 31, ty = threadIdx.x >> 5;
  int n0 = blockIdx.x * 32, k0 = blockIdx.y * 32;
  #pragma unroll
  for (int i = ty; i < 32; i += 8)
    t[i][tx] = W[(size_t)(k0 + i) * N + n0 + tx];
  __syncthreads();
  #pragma unroll
  for (int i = ty; i < 32; i += 8)
    WT[(size_t)(n0 + i) * K + k0 + tx] = __float2bfloat16(t[tx][i]);
}

// ---------------- transpose bf16 [K][N] -> bf16 [N][K] ----------------
__global__ void transpose_bf16(const __hip_bfloat16* __restrict__ W, __hip_bfloat16* __restrict__ WT,
                               int K, int N) {
  __shared__ __hip_bfloat16 t[32][33];
  int tx = threadIdx.x & 31, ty = threadIdx.x >> 5;
  int n0 = blockIdx.x * 32, k0 = blockIdx.y * 32;
  #pragma unroll
  for (int i = ty; i < 32; i += 8)
    t[i][tx] = W[(size_t)(k0 + i) * N + n0 + tx];
  __syncthreads();
  #pragma unroll
  for (int i = ty; i < 32; i += 8)
    WT[(size_t)(n0 + i) * K + k0 + tx] = t[tx][i];
}

// ---------------- m97-structure GEMM: C = A[M,K] * Bt[N,K]^T ----------------
// MODE 0: QKV epilogue (bf16 Q/K/V outs + bias, Q scaled by 1/sqrt(HD))
// MODE 1: fp32 out + bias (O projection)
template<int MODE>
__global__ __launch_bounds__(256, 2) void gemm_bt(
    const __hip_bfloat16* __restrict__ A, const __hip_bfloat16* __restrict__ Bt,
    int M, int N, int K,
    __hip_bfloat16* __restrict__ oQ, __hip_bfloat16* __restrict__ oK, __hip_bfloat16* __restrict__ oV,
    const float* __restrict__ bQ, const float* __restrict__ bK, const float* __restrict__ bV,
    float* __restrict__ oF, const float* __restrict__ bF) {
  __shared__ __align__(16) __hip_bfloat16 As[128 * 32];
  __shared__ __align__(16) __hip_bfloat16 Bs[128 * 32];
  const int tid = threadIdx.x, wid = tid >> 6, lane = tid & 63;
  const int g = lane >> 4, c = lane & 15;
  const int wm = wid >> 1, wn = wid & 1;
  const int m0 = blockIdx.y * 128, n0 = blockIdx.x * 128;
  const __hip_bfloat16* Ab = A + (size_t)m0 * K;
  const __hip_bfloat16* Bb = Bt + (size_t)n0 * K;
  f32x4 acc[4][4] = {};
  for (int k0 = 0; k0 < K; k0 += 32) {
    #pragma unroll
    for (int call = 0; call < 2; ++call) {
      int ci = wid * 128 + call * 64 + lane;  // 16B chunk index in [0,512)
      gl2lds16(Ab + (size_t)(ci >> 2) * K + k0 + (ci & 3) * 8,
               (char*)As + (wid * 128 + call * 64) * 16);
      gl2lds16(Bb + (size_t)(ci >> 2) * K + k0 + (ci & 3) * 8,
               (char*)Bs + (wid * 128 + call * 64) * 16);
    }
    __syncthreads();
    short8 af[4], bfr[4];
    #pragma unroll
    for (int t = 0; t < 4; ++t) af[t]  = *(const short8*)&As[(wm * 64 + t * 16 + c) * 32 + g * 8];
    #pragma unroll
    for (int t = 0; t < 4; ++t) bfr[t] = *(const short8*)&Bs[(wn * 64 + t * 16 + c) * 32 + g * 8];
    #pragma unroll
    for (int i = 0; i < 4; ++i)
      #pragma unroll
      for (int j = 0; j < 4; ++j)
        acc[i][j] = __builtin_amdgcn_mfma_f32_16x16x32_bf16(af[i], bfr[j], acc[i][j], 0, 0, 0);
    __syncthreads();
  }
  #pragma unroll
  for (int i = 0; i < 4; ++i) {
    #pragma unroll
    for (int j = 0; j < 4; ++j) {
      int col = n0 + wn * 64 + j * 16 + c;
      #pragma unroll
      for (int r = 0; r < 4; ++r) {
        int row = m0 + wm * 64 + i * 16 + g * 4 + r;
        float v = acc[i][j][r];
        if (MODE == 0) {
          if (col < EMB) {
            oQ[(size_t)row * EMB + col] = __float2bfloat16((v + bQ[col]) * 0.08838834764831845f);
          } else if (col < EMB + KVD) {
            oK[(size_t)row * KVD + (col - EMB)] = __float2bfloat16(v + bK[col - EMB]);
          } else {
            oV[(size_t)row * KVD + (col - EMB - KVD)] = __float2bfloat16(v + bV[col - EMB - KVD]);
          }
        } else {
          oF[(size_t)row * EMB + col] = v + bF[col];
        }
      }
    }
  }
}

// ---------------- flash attention (causal, GQA) ----------------
// Q: [S][EMB] bf16 (pre-scaled), K: [S][KVD] bf16, Vt: [NKV*HD][S] bf16, ctx: [S][EMB] bf16
__global__ __launch_bounds__(256, 2) void attn_kernel(
    const __hip_bfloat16* __restrict__ Q, const __hip_bfloat16* __restrict__ Kb,
    const __hip_bfloat16* __restrict__ Vt, __hip_bfloat16* __restrict__ ctx) {
  __shared__ __align__(16) __hip_bfloat16 Ks[64 * 128];   // [kv][d], XOR-swizzled
  __shared__ __align__(16) __hip_bfloat16 Vs[128 * 64];   // [d][kv], XOR-swizzled
  __shared__ __align__(16) __hip_bfloat16 Ps[4][16 * 72]; // per-wave P, stride 72 (144B = 4 mod 32 dw)
  const int h = blockIdx.y, qb = blockIdx.x;
  const int kvh = h >> 2;
  const int tid = threadIdx.x, wid = tid >> 6, lane = tid & 63;
  const int g = lane >> 4, c = lane & 15;
  const int qrow = qb * 64 + wid * 16 + c;
  short8 qf[4];
  #pragma unroll
  for (int ks = 0; ks < 4; ++ks)
    qf[ks] = *(const short8*)&Q[(size_t)qrow * EMB + h * HD + ks * 32 + g * 8];
  f32x4 o[8] = {};
  float mreg[4] = {-1e30f, -1e30f, -1e30f, -1e30f};
  float lreg[4] = {0.f, 0.f, 0.f, 0.f};
  const int ntiles = qb + 1;
  for (int t = 0; t < ntiles; ++t) {
    const int kv0 = t * 64;
    // stage K (64x128) and V^T (128x64), linear LDS dest + pre-swizzled global source
    #pragma unroll
    for (int call = 0; call < 4; ++call) {
      int ci = wid * 256 + call * 64 + lane;  // 16B chunk in [0,1024)
      int r = ci >> 4, sl = ci & 15;
      gl2lds16(Kb + (size_t)(kv0 + r) * KVD + kvh * HD + ((sl ^ (r & 7)) << 3),
               (char*)Ks + (wid * 256 + call * 64) * 16);
      int d = ci >> 3, vs = ci & 7;
      gl2lds16(Vt + (size_t)(kvh * HD + d) * S_LEN + kv0 + ((vs ^ (d & 7)) << 3),
               (char*)Vs + (wid * 256 + call * 64) * 16);
    }
    __syncthreads();
    // S = Q * K^T  (16 q-rows x 64 kv)
    f32x4 sc[4] = {};
    #pragma unroll
    for (int ks = 0; ks < 4; ++ks) {
      #pragma unroll
      for (int nt = 0; nt < 4; ++nt) {
        int kvr = nt * 16 + c;
        int byt = ((kvr << 8) + (ks << 6) + (g << 4)) ^ ((kvr & 7) << 4);
        short8 kf = *(const short8*)((const char*)Ks + byt);
        sc[nt] = __builtin_amdgcn_mfma_f32_16x16x32_bf16(qf[ks], kf, sc[nt], 0, 0, 0);
      }
    }
    if (t == ntiles - 1) {  // diagonal tile: causal mask
      #pragma unroll
      for (int nt = 0; nt < 4; ++nt)
        #pragma unroll
        for (int r = 0; r < 4; ++r)
          if (kv0 + nt * 16 + c > qb * 64 + wid * 16 + g * 4 + r) sc[nt][r] = -1e30f;
    }
    // online softmax: rows live in (g, reg), cols in (c, nt)
    float mx[4], rs[4], corr[4];
    #pragma unroll
    for (int r = 0; r < 4; ++r)
      mx[r] = fmaxf(fmaxf(sc[0][r], sc[1][r]), fmaxf(sc[2][r], sc[3][r]));
    #pragma unroll
    for (int d = 1; d < 16; d <<= 1)
      #pragma unroll
      for (int r = 0; r < 4; ++r) mx[r] = fmaxf(mx[r], __shfl_xor(mx[r], d, 64));
    #pragma unroll
    for (int r = 0; r < 4; ++r) {
      float mn = fmaxf(mreg[r], mx[r]);
      corr[r] = __expf(mreg[r] - mn);
      mreg[r] = mn;
    }
    #pragma unroll
    for (int nt = 0; nt < 4; ++nt)
      #pragma unroll
      for (int r = 0; r < 4; ++r) sc[nt][r] = __expf(sc[nt][r] - mreg[r]);
    #pragma unroll
    for (int r = 0; r < 4; ++r) rs[r] = sc[0][r] + sc[1][r] + sc[2][r] + sc[3][r];
    #pragma unroll
    for (int d = 1; d < 16; d <<= 1)
      #pragma unroll
      for (int r = 0; r < 4; ++r) rs[r] += __shfl_xor(rs[r], d, 64);
    #pragma unroll
    for (int r = 0; r < 4; ++r) lreg[r] = lreg[r] * corr[r] + rs[r];
    #pragma unroll
    for (int dt = 0; dt < 8; ++dt)
      #pragma unroll
      for (int r = 0; r < 4; ++r) o[dt][r] *= corr[r];
    // P -> LDS (relayout C-frag -> A-frag)
    #pragma unroll
    for (int nt = 0; nt < 4; ++nt)
      #pragma unroll
      for (int r = 0; r < 4; ++r)
        Ps[wid][(g * 4 + r) * 72 + nt * 16 + c] = __float2bfloat16(sc[nt][r]);
    __syncthreads();
    // O += P * V
    #pragma unroll
    for (int k2 = 0; k2 < 2; ++k2) {
      short8 pf = *(const short8*)&Ps[wid][c * 72 + k2 * 32 + g * 8];
      #pragma unroll
      for (int dt = 0; dt < 8; ++dt) {
        int d = dt * 16 + c;
        int byt = ((d << 7) + (k2 << 6) + (g << 4)) ^ ((d & 7) << 4);
        short8 vf = *(const short8*)((const char*)Vs + byt);
        o[dt] = __builtin_amdgcn_mfma_f32_16x16x32_bf16(pf, vf, o[dt], 0, 0, 0);
      }
    }
    __syncthreads();
  }
  float inv[4];
  #pragma unroll
  for (int r = 0; r < 4; ++r) inv[r] = 1.f / lreg[r];
  #pragma unroll
  for (int dt = 0; dt < 8; ++dt)
    #pragma unroll
    for (int r = 0; r < 4; ++r)
      ctx[(size_t)(qb * 64 + wid * 16 + g * 4 + r) * EMB + h * HD + dt * 16 + c] =
          __float2bfloat16(o[dt][r] * inv[r]);
}

extern "C" void kernel_launch(void* const* d_in, const int* in_sizes, int n_in,
                              void* d_out, int out_size, void* d_ws, size_t ws_size,
                              hipStream_t stream) {
  const float* x  = (const float*)d_in[0];
  // d_in[1] = causal mask (static, reimplemented in-kernel)
  const float* wq = (const float*)d_in[2];
  const float* qb = (const float*)d_in[3];
  const float* wk = (const float*)d_in[4];
  const float* kb = (const float*)d_in[5];
  const float* wv = (const float*)d_in[6];
  const float* vb = (const float*)d_in[7];
  const float* wo = (const float*)d_in[8];
  const float* ob = (const float*)d_in[9];

  char* ws = (char*)d_ws;
  __hip_bfloat16* x_bf  = (__hip_bfloat16*)(ws);              // 16 MB
  __hip_bfloat16* wqkvT = (__hip_bfloat16*)(ws + 16777216);   // 12 MB [3072][2048]
  __hip_bfloat16* woT   = (__hip_bfloat16*)(ws + 29360128);   // 8 MB  [2048][2048]
  __hip_bfloat16* q_bf  = (__hip_bfloat16*)(ws + 37748736);   // 16 MB [4096][2048]
  __hip_bfloat16* k_bf  = (__hip_bfloat16*)(ws + 54525952);   // 4 MB  [4096][512]
  __hip_bfloat16* v_bf  = (__hip_bfloat16*)(ws + 58720256);   // 4 MB  [4096][512]
  __hip_bfloat16* vT    = (__hip_bfloat16*)(ws + 62914560);   // 4 MB  [512][4096]
  __hip_bfloat16* ctx   = (__hip_bfloat16*)(ws + 67108864);   // 16 MB [4096][2048]

  cvt_f32_bf16<<<2048, 256, 0, stream>>>(x, x_bf, S_LEN * EMB);
  transpose_f32_bf16<<<dim3(64, 64), 256, 0, stream>>>(wq, wqkvT, EMB, EMB);
  transpose_f32_bf16<<<dim3(16, 64), 256, 0, stream>>>(wk, wqkvT + (size_t)EMB * EMB, EMB, KVD);
  transpose_f32_bf16<<<dim3(16, 64), 256, 0, stream>>>(wv, wqkvT + (size_t)(EMB + KVD) * EMB, EMB, KVD);
  transpose_f32_bf16<<<dim3(64, 64), 256, 0, stream>>>(wo, woT, EMB, EMB);

  gemm_bt<0><<<dim3(24, 32), 256, 0, stream>>>(x_bf, wqkvT, S_LEN, 3072, EMB,
      q_bf, k_bf, v_bf, qb, kb, vb, nullptr, nullptr);

  transpose_bf16<<<dim3(16, 128), 256, 0, stream>>>(v_bf, vT, S_LEN, KVD);

  attn_kernel<<<dim3(64, NH), 256, 0, stream>>>(q_bf, k_bf, vT, ctx);

  gemm_bt<1><<<dim3(16, 32), 256, 0, stream>>>(ctx, woT, S_LEN, EMB, EMB,
      nullptr, nullptr, nullptr, nullptr, nullptr, nullptr, (float*)d_out, ob);
}

// Round 4
// 454.017 us; speedup vs baseline: 1.2677x; 1.2677x over previous
//
#include <hip/hip_runtime.h>
#include <hip/hip_bf16.h>
#include <stdint.h>

#define S_LEN 4096
#define EMB   2048
#define KVD   512
#define HD    128
#define NH    16

typedef __attribute__((ext_vector_type(8))) short short8;
typedef __attribute__((ext_vector_type(4))) float f32x4;

#define AS1 __attribute__((address_space(1)))
#define AS3 __attribute__((address_space(3)))

__device__ __forceinline__ void gl2lds16(const void* g, void* l) {
  __builtin_amdgcn_global_load_lds((AS1 void*)g, (AS3 void*)l, 16, 0, 0);
}

__device__ __forceinline__ unsigned short f2bu(float f) {
  __hip_bfloat16 h = __float2bfloat16(f);
  unsigned short u;
  __builtin_memcpy(&u, &h, 2);
  return u;
}

// ---------------- fp32 -> bf16 convert (vectorized) ----------------
__global__ void cvt_f32_bf16(const float* __restrict__ in, __hip_bfloat16* __restrict__ out, int n) {
  int i = blockIdx.x * blockDim.x + threadIdx.x;
  int stride = gridDim.x * blockDim.x;
  for (int idx = i * 4; idx < n; idx += stride * 4) {
    float4 f = *(const float4*)(in + idx);
    ushort4 u4 = make_ushort4(f2bu(f.x), f2bu(f.y), f2bu(f.z), f2bu(f.w));
    *reinterpret_cast<ushort4*>(out + idx) = u4;
  }
}

// ---------------- transpose fp32 [K][N] -> bf16 [N][K] ----------------
__global__ void transpose_f32_bf16(const float* __restrict__ W, __hip_bfloat16* __restrict__ WT,
                                   int K, int N) {
  __shared__ float t[32][33];
  int tx = threadIdx.x & 31, ty = threadIdx.x >> 5;
  int n0 = blockIdx.x * 32, k0 = blockIdx.y * 32;
  #pragma unroll
  for (int i = ty; i < 32; i += 8)
    t[i][tx] = W[(size_t)(k0 + i) * N + n0 + tx];
  __syncthreads();
  #pragma unroll
  for (int i = ty; i < 32; i += 8)
    WT[(size_t)(n0 + i) * K + k0 + tx] = __float2bfloat16(t[tx][i]);
}

// ---------------- transpose bf16 [K][N] -> bf16 [N][K] ----------------
__global__ void transpose_bf16(const __hip_bfloat16* __restrict__ W, __hip_bfloat16* __restrict__ WT,
                               int K, int N) {
  __shared__ __hip_bfloat16 t[32][33];
  int tx = threadIdx.x & 31, ty = threadIdx.x >> 5;
  int n0 = blockIdx.x * 32, k0 = blockIdx.y * 32;
  #pragma unroll
  for (int i = ty; i < 32; i += 8)
    t[i][tx] = W[(size_t)(k0 + i) * N + n0 + tx];
  __syncthreads();
  #pragma unroll
  for (int i = ty; i < 32; i += 8)
    WT[(size_t)(n0 + i) * K + k0 + tx] = t[tx][i];
}

// ---------------- m97-structure GEMM: C = A[M,K] * Bt[N,K]^T ----------------
template<int MODE>
__global__ __launch_bounds__(256, 2) void gemm_bt(
    const __hip_bfloat16* __restrict__ A, const __hip_bfloat16* __restrict__ Bt,
    int M, int N, int K,
    __hip_bfloat16* __restrict__ oQ, __hip_bfloat16* __restrict__ oK, __hip_bfloat16* __restrict__ oV,
    const float* __restrict__ bQ, const float* __restrict__ bK, const float* __restrict__ bV,
    float* __restrict__ oF, const float* __restrict__ bF) {
  __shared__ __align__(16) __hip_bfloat16 As[128 * 32];
  __shared__ __align__(16) __hip_bfloat16 Bs[128 * 32];
  const int tid = threadIdx.x, wid = tid >> 6, lane = tid & 63;
  const int g = lane >> 4, c = lane & 15;
  const int wm = wid >> 1, wn = wid & 1;
  const int m0 = blockIdx.y * 128, n0 = blockIdx.x * 128;
  const __hip_bfloat16* Ab = A + (size_t)m0 * K;
  const __hip_bfloat16* Bb = Bt + (size_t)n0 * K;
  f32x4 acc[4][4] = {};
  for (int k0 = 0; k0 < K; k0 += 32) {
    #pragma unroll
    for (int call = 0; call < 2; ++call) {
      int ci = wid * 128 + call * 64 + lane;  // 16B chunk index in [0,512)
      gl2lds16(Ab + (size_t)(ci >> 2) * K + k0 + (ci & 3) * 8,
               (char*)As + (wid * 128 + call * 64) * 16);
      gl2lds16(Bb + (size_t)(ci >> 2) * K + k0 + (ci & 3) * 8,
               (char*)Bs + (wid * 128 + call * 64) * 16);
    }
    __syncthreads();
    short8 af[4], bfr[4];
    #pragma unroll
    for (int t = 0; t < 4; ++t) af[t]  = *(const short8*)&As[(wm * 64 + t * 16 + c) * 32 + g * 8];
    #pragma unroll
    for (int t = 0; t < 4; ++t) bfr[t] = *(const short8*)&Bs[(wn * 64 + t * 16 + c) * 32 + g * 8];
    #pragma unroll
    for (int i = 0; i < 4; ++i)
      #pragma unroll
      for (int j = 0; j < 4; ++j)
        acc[i][j] = __builtin_amdgcn_mfma_f32_16x16x32_bf16(af[i], bfr[j], acc[i][j], 0, 0, 0);
    __syncthreads();
  }
  #pragma unroll
  for (int i = 0; i < 4; ++i) {
    #pragma unroll
    for (int j = 0; j < 4; ++j) {
      int col = n0 + wn * 64 + j * 16 + c;
      #pragma unroll
      for (int r = 0; r < 4; ++r) {
        int row = m0 + wm * 64 + i * 16 + g * 4 + r;
        float v = acc[i][j][r];
        if (MODE == 0) {
          if (col < EMB) {
            oQ[(size_t)row * EMB + col] = __float2bfloat16((v + bQ[col]) * 0.08838834764831845f);
          } else if (col < EMB + KVD) {
            oK[(size_t)row * KVD + (col - EMB)] = __float2bfloat16(v + bK[col - EMB]);
          } else {
            oV[(size_t)row * KVD + (col - EMB - KVD)] = __float2bfloat16(v + bV[col - EMB - KVD]);
          }
        } else {
          oF[(size_t)row * EMB + col] = v + bF[col];
        }
      }
    }
  }
}

// ---------------- flash attention (causal, GQA) ----------------
// Balanced pairing: block i in [0,32) handles Q-tiles i and 63-i -> 65 KV-tile
// units for every block. 512 blocks = 2/CU, all co-resident, no tail.
// 2-phase double-buffered K/V: issue STAGE(t+1) before compute(t); one
// vmcnt(0)+barrier per tile (T3 minimum recipe). Ps is per-wave -> no barrier.

__device__ __forceinline__ void stage_kv(const __hip_bfloat16* __restrict__ Kb,
                                         const __hip_bfloat16* __restrict__ Vt,
                                         int kvh, int kv0, int wid,
                                         __hip_bfloat16* Ks, __hip_bfloat16* Vs) {
  const int lane = threadIdx.x & 63;
  #pragma unroll
  for (int call = 0; call < 4; ++call) {
    int ci = wid * 256 + call * 64 + lane;  // 16B chunk in [0,1024)
    int r = ci >> 4, sl = ci & 15;
    gl2lds16(Kb + (size_t)(kv0 + r) * KVD + kvh * HD + ((sl ^ (r & 7)) << 3),
             (char*)Ks + (wid * 256 + call * 64) * 16);
    int d = ci >> 3, vs = ci & 7;
    gl2lds16(Vt + (size_t)(kvh * HD + d) * S_LEN + kv0 + ((vs ^ (d & 7)) << 3),
             (char*)Vs + (wid * 256 + call * 64) * 16);
  }
}

__device__ __forceinline__ void attn_qtile(
    int qb, int h, int kvh, int wid, int g, int c,
    const __hip_bfloat16* __restrict__ Q, const __hip_bfloat16* __restrict__ Kb,
    const __hip_bfloat16* __restrict__ Vt, __hip_bfloat16* __restrict__ ctx,
    __hip_bfloat16 (*Ks)[64 * 128], __hip_bfloat16 (*Vs)[128 * 64],
    __hip_bfloat16* Pw) {
  const int qrow = qb * 64 + wid * 16 + c;
  short8 qf[4];
  #pragma unroll
  for (int ks = 0; ks < 4; ++ks)
    qf[ks] = *(const short8*)&Q[(size_t)qrow * EMB + h * HD + ks * 32 + g * 8];
  f32x4 o[8] = {};
  float mreg[4] = {-1e30f, -1e30f, -1e30f, -1e30f};
  float lreg[4] = {0.f, 0.f, 0.f, 0.f};
  const int ntiles = qb + 1;
  stage_kv(Kb, Vt, kvh, 0, wid, Ks[0], Vs[0]);
  asm volatile("s_waitcnt vmcnt(0)" ::: "memory");
  __syncthreads();
  int buf = 0;
  for (int t = 0; t < ntiles; ++t) {
    const int kv0 = t * 64;
    if (t + 1 < ntiles)
      stage_kv(Kb, Vt, kvh, kv0 + 64, wid, Ks[buf ^ 1], Vs[buf ^ 1]);
    const char* Kbase = (const char*)Ks[buf];
    const char* Vbase = (const char*)Vs[buf];
    // S = Q * K^T  (16 q-rows x 64 kv)
    f32x4 sc[4] = {};
    #pragma unroll
    for (int ks = 0; ks < 4; ++ks) {
      #pragma unroll
      for (int nt = 0; nt < 4; ++nt) {
        int kvr = nt * 16 + c;
        int byt = ((kvr << 8) + (ks << 6) + (g << 4)) ^ ((kvr & 7) << 4);
        short8 kf = *(const short8*)(Kbase + byt);
        sc[nt] = __builtin_amdgcn_mfma_f32_16x16x32_bf16(qf[ks], kf, sc[nt], 0, 0, 0);
      }
    }
    if (t == ntiles - 1) {  // diagonal tile: causal mask
      #pragma unroll
      for (int nt = 0; nt < 4; ++nt)
        #pragma unroll
        for (int r = 0; r < 4; ++r)
          if (kv0 + nt * 16 + c > qb * 64 + wid * 16 + g * 4 + r) sc[nt][r] = -1e30f;
    }
    // online softmax: rows live in (g, reg), cols in (c, nt)
    float mx[4], rs[4], corr[4];
    #pragma unroll
    for (int r = 0; r < 4; ++r)
      mx[r] = fmaxf(fmaxf(sc[0][r], sc[1][r]), fmaxf(sc[2][r], sc[3][r]));
    #pragma unroll
    for (int d = 1; d < 16; d <<= 1)
      #pragma unroll
      for (int r = 0; r < 4; ++r) mx[r] = fmaxf(mx[r], __shfl_xor(mx[r], d, 64));
    #pragma unroll
    for (int r = 0; r < 4; ++r) {
      float mn = fmaxf(mreg[r], mx[r]);
      corr[r] = __expf(mreg[r] - mn);
      mreg[r] = mn;
    }
    #pragma unroll
    for (int nt = 0; nt < 4; ++nt)
      #pragma unroll
      for (int r = 0; r < 4; ++r) sc[nt][r] = __expf(sc[nt][r] - mreg[r]);
    #pragma unroll
    for (int r = 0; r < 4; ++r) rs[r] = sc[0][r] + sc[1][r] + sc[2][r] + sc[3][r];
    #pragma unroll
    for (int d = 1; d < 16; d <<= 1)
      #pragma unroll
      for (int r = 0; r < 4; ++r) rs[r] += __shfl_xor(rs[r], d, 64);
    #pragma unroll
    for (int r = 0; r < 4; ++r) lreg[r] = lreg[r] * corr[r] + rs[r];
    #pragma unroll
    for (int dt = 0; dt < 8; ++dt)
      #pragma unroll
      for (int r = 0; r < 4; ++r) o[dt][r] *= corr[r];
    // P -> per-wave LDS (C-frag -> A-frag relayout); intra-wave only, no barrier
    #pragma unroll
    for (int nt = 0; nt < 4; ++nt)
      #pragma unroll
      for (int r = 0; r < 4; ++r)
        Pw[(g * 4 + r) * 72 + nt * 16 + c] = __float2bfloat16(sc[nt][r]);
    // O += P * V
    #pragma unroll
    for (int k2 = 0; k2 < 2; ++k2) {
      short8 pf = *(const short8*)&Pw[c * 72 + k2 * 32 + g * 8];
      #pragma unroll
      for (int dt = 0; dt < 8; ++dt) {
        int d = dt * 16 + c;
        int byt = ((d << 7) + (k2 << 6) + (g << 4)) ^ ((d & 7) << 4);
        short8 vf = *(const short8*)(Vbase + byt);
        o[dt] = __builtin_amdgcn_mfma_f32_16x16x32_bf16(pf, vf, o[dt], 0, 0, 0);
      }
    }
    asm volatile("s_waitcnt vmcnt(0)" ::: "memory");
    __syncthreads();
    buf ^= 1;
  }
  float inv[4];
  #pragma unroll
  for (int r = 0; r < 4; ++r) inv[r] = 1.f / lreg[r];
  #pragma unroll
  for (int dt = 0; dt < 8; ++dt)
    #pragma unroll
    for (int r = 0; r < 4; ++r)
      ctx[(size_t)(qb * 64 + wid * 16 + g * 4 + r) * EMB + h * HD + dt * 16 + c] =
          __float2bfloat16(o[dt][r] * inv[r]);
}

__global__ __launch_bounds__(256, 2) void attn_kernel(
    const __hip_bfloat16* __restrict__ Q, const __hip_bfloat16* __restrict__ Kb,
    const __hip_bfloat16* __restrict__ Vt, __hip_bfloat16* __restrict__ ctx) {
  __shared__ __align__(16) __hip_bfloat16 Ks[2][64 * 128];   // [kv][d], XOR-swizzled
  __shared__ __align__(16) __hip_bfloat16 Vs[2][128 * 64];   // [d][kv], XOR-swizzled
  __shared__ __align__(16) __hip_bfloat16 Ps[4][16 * 72];    // per-wave P, stride 72
  const int h = blockIdx.y, i = blockIdx.x;
  const int kvh = h >> 2;
  const int wid = threadIdx.x >> 6, lane = threadIdx.x & 63;
  const int g = lane >> 4, c = lane & 15;
  attn_qtile(i, h, kvh, wid, g, c, Q, Kb, Vt, ctx, Ks, Vs, Ps[wid]);
  attn_qtile(63 - i, h, kvh, wid, g, c, Q, Kb, Vt, ctx, Ks, Vs, Ps[wid]);
}

extern "C" void kernel_launch(void* const* d_in, const int* in_sizes, int n_in,
                              void* d_out, int out_size, void* d_ws, size_t ws_size,
                              hipStream_t stream) {
  const float* x  = (const float*)d_in[0];
  // d_in[1] = causal mask (static, reimplemented in-kernel)
  const float* wq = (const float*)d_in[2];
  const float* qb = (const float*)d_in[3];
  const float* wk = (const float*)d_in[4];
  const float* kb = (const float*)d_in[5];
  const float* wv = (const float*)d_in[6];
  const float* vb = (const float*)d_in[7];
  const float* wo = (const float*)d_in[8];
  const float* ob = (const float*)d_in[9];

  char* ws = (char*)d_ws;
  __hip_bfloat16* x_bf  = (__hip_bfloat16*)(ws);              // 16 MB
  __hip_bfloat16* wqkvT = (__hip_bfloat16*)(ws + 16777216);   // 12 MB [3072][2048]
  __hip_bfloat16* woT   = (__hip_bfloat16*)(ws + 29360128);   // 8 MB  [2048][2048]
  __hip_bfloat16* q_bf  = (__hip_bfloat16*)(ws + 37748736);   // 16 MB [4096][2048]
  __hip_bfloat16* k_bf  = (__hip_bfloat16*)(ws + 54525952);   // 4 MB  [4096][512]
  __hip_bfloat16* v_bf  = (__hip_bfloat16*)(ws + 58720256);   // 4 MB  [4096][512]
  __hip_bfloat16* vT    = (__hip_bfloat16*)(ws + 62914560);   // 4 MB  [512][4096]
  __hip_bfloat16* ctx   = (__hip_bfloat16*)(ws + 67108864);   // 16 MB [4096][2048]

  cvt_f32_bf16<<<2048, 256, 0, stream>>>(x, x_bf, S_LEN * EMB);
  transpose_f32_bf16<<<dim3(64, 64), 256, 0, stream>>>(wq, wqkvT, EMB, EMB);
  transpose_f32_bf16<<<dim3(16, 64), 256, 0, stream>>>(wk, wqkvT + (size_t)EMB * EMB, EMB, KVD);
  transpose_f32_bf16<<<dim3(16, 64), 256, 0, stream>>>(wv, wqkvT + (size_t)(EMB + KVD) * EMB, EMB, KVD);
  transpose_f32_bf16<<<dim3(64, 64), 256, 0, stream>>>(wo, woT, EMB, EMB);

  gemm_bt<0><<<dim3(24, 32), 256, 0, stream>>>(x_bf, wqkvT, S_LEN, 3072, EMB,
      q_bf, k_bf, v_bf, qb, kb, vb, nullptr, nullptr);

  transpose_bf16<<<dim3(16, 128), 256, 0, stream>>>(v_bf, vT, S_LEN, KVD);

  attn_kernel<<<dim3(32, NH), 256, 0, stream>>>(q_bf, k_bf, vT, ctx);

  gemm_bt<1><<<dim3(16, 32), 256, 0, stream>>>(ctx, woT, S_LEN, EMB, EMB,
      nullptr, nullptr, nullptr, nullptr, nullptr, nullptr, (float*)d_out, ob);
}

// Round 13
// 414.328 us; speedup vs baseline: 1.3891x; 1.0958x over previous
//
#include <hip/hip_runtime.h>
#include <hip/hip_bf16.h>
#include <stdint.h>
#include <math.h>

#define S_LEN 4096
#define EMB   2048
#define KVD   512
#define HD    128
#define NH    16

typedef __attribute__((ext_vector_type(8))) short short8;
typedef __attribute__((ext_vector_type(4))) float f32x4;

#define AS1 __attribute__((address_space(1)))
#define AS3 __attribute__((address_space(3)))

__device__ __forceinline__ void gl2lds16(const void* g, void* l) {
  __builtin_amdgcn_global_load_lds((AS1 void*)g, (AS3 void*)l, 16, 0, 0);
}

// hardware exp2 (v_exp_f32). __exp2f does NOT exist on this toolchain (r9).
__device__ __forceinline__ float fexp2(float x) {
#if __has_builtin(__builtin_amdgcn_exp2f)
  return __builtin_amdgcn_exp2f(x);
#else
  return exp2f(x);
#endif
}

__device__ __forceinline__ unsigned short f2bu(float f) {
  __hip_bfloat16 h = __float2bfloat16(f);
  unsigned short u;
  __builtin_memcpy(&u, &h, 2);
  return u;
}

// ---------------- fp32 -> bf16 convert (vectorized) ----------------
__global__ void cvt_f32_bf16(const float* __restrict__ in, __hip_bfloat16* __restrict__ out, int n) {
  int i = blockIdx.x * blockDim.x + threadIdx.x;
  int stride = gridDim.x * blockDim.x;
  for (int idx = i * 4; idx < n; idx += stride * 4) {
    float4 f = *(const float4*)(in + idx);
    ushort4 u4 = make_ushort4(f2bu(f.x), f2bu(f.y), f2bu(f.z), f2bu(f.w));
    *reinterpret_cast<ushort4*>(out + idx) = u4;
  }
}

// ------- merged weight transpose fp32 [K=EMB][N] -> bf16 [N][EMB] -------
// z=0: wq -> wqkvT[0..], z=1: wo -> woT, z=2: wk -> wqkvT+EMB*EMB,
// z=3: wv -> wqkvT+(EMB+KVD)*EMB. Narrow weights (N=KVD) early-return
// (block-uniform condition, before any barrier).
__global__ void transpose_weights(const float* __restrict__ wq, const float* __restrict__ wk,
                                  const float* __restrict__ wv, const float* __restrict__ wo,
                                  __hip_bfloat16* __restrict__ wqkvT, __hip_bfloat16* __restrict__ woT) {
  const int z = blockIdx.z;
  const float* W;
  __hip_bfloat16* WT;
  int N;
  if (z == 0)      { W = wq; WT = wqkvT;                              N = EMB; }
  else if (z == 1) { W = wo; WT = woT;                                N = EMB; }
  else if (z == 2) { W = wk; WT = wqkvT + (size_t)EMB * EMB;          N = KVD; }
  else             { W = wv; WT = wqkvT + (size_t)(EMB + KVD) * EMB;  N = KVD; }
  int n0 = blockIdx.x * 32, k0 = blockIdx.y * 32;
  if (n0 >= N) return;
  __shared__ float t[32][33];
  int tx = threadIdx.x & 31, ty = threadIdx.x >> 5;
  #pragma unroll
  for (int i = ty; i < 32; i += 8)
    t[i][tx] = W[(size_t)(k0 + i) * N + n0 + tx];
  __syncthreads();
  #pragma unroll
  for (int i = ty; i < 32; i += 8)
    WT[(size_t)(n0 + i) * EMB + k0 + tx] = __float2bfloat16(t[tx][i]);
}

// ---------------- m97-structure GEMM: C = A[M,K] * Bt[N,K]^T ----------------
// MODE 0: QKV epilogue — Q (exp2-domain prescaled) and K row-major bf16;
//         V written TRANSPOSED into vT[d][s] (fuses the old transpose_bf16).
// MODE 1: fp32 out + bias (O projection)
template<int MODE>
__global__ __launch_bounds__(256, 2) void gemm_bt(
    const __hip_bfloat16* __restrict__ A, const __hip_bfloat16* __restrict__ Bt,
    int M, int N, int K,
    __hip_bfloat16* __restrict__ oQ, __hip_bfloat16* __restrict__ oK, __hip_bfloat16* __restrict__ oVt,
    const float* __restrict__ bQ, const float* __restrict__ bK, const float* __restrict__ bV,
    float* __restrict__ oF, const float* __restrict__ bF) {
  __shared__ __align__(16) __hip_bfloat16 As[128 * 32];
  __shared__ __align__(16) __hip_bfloat16 Bs[128 * 32];
  const int tid = threadIdx.x, wid = tid >> 6, lane = tid & 63;
  const int g = lane >> 4, c = lane & 15;
  const int wm = wid >> 1, wn = wid & 1;
  const int m0 = blockIdx.y * 128, n0 = blockIdx.x * 128;
  const __hip_bfloat16* Ab = A + (size_t)m0 * K;
  const __hip_bfloat16* Bb = Bt + (size_t)n0 * K;
  f32x4 acc[4][4] = {};
  for (int k0 = 0; k0 < K; k0 += 32) {
    #pragma unroll
    for (int call = 0; call < 2; ++call) {
      int ci = wid * 128 + call * 64 + lane;  // 16B chunk index in [0,512)
      gl2lds16(Ab + (size_t)(ci >> 2) * K + k0 + (ci & 3) * 8,
               (char*)As + (wid * 128 + call * 64) * 16);
      gl2lds16(Bb + (size_t)(ci >> 2) * K + k0 + (ci & 3) * 8,
               (char*)Bs + (wid * 128 + call * 64) * 16);
    }
    __syncthreads();
    short8 af[4], bfr[4];
    #pragma unroll
    for (int t = 0; t < 4; ++t) af[t]  = *(const short8*)&As[(wm * 64 + t * 16 + c) * 32 + g * 8];
    #pragma unroll
    for (int t = 0; t < 4; ++t) bfr[t] = *(const short8*)&Bs[(wn * 64 + t * 16 + c) * 32 + g * 8];
    #pragma unroll
    for (int i = 0; i < 4; ++i)
      #pragma unroll
      for (int j = 0; j < 4; ++j)
        acc[i][j] = __builtin_amdgcn_mfma_f32_16x16x32_bf16(af[i], bfr[j], acc[i][j], 0, 0, 0);
    __syncthreads();
  }
  #pragma unroll
  for (int i = 0; i < 4; ++i) {
    #pragma unroll
    for (int j = 0; j < 4; ++j) {
      int col = n0 + wn * 64 + j * 16 + c;
      #pragma unroll
      for (int r = 0; r < 4; ++r) {
        int row = m0 + wm * 64 + i * 16 + g * 4 + r;
        float v = acc[i][j][r];
        if (MODE == 0) {
          if (col < EMB) {
            // 1/sqrt(128) * log2(e): softmax runs in exp2 domain
            oQ[(size_t)row * EMB + col] = __float2bfloat16((v + bQ[col]) * 0.12751743f);
          } else if (col < EMB + KVD) {
            oK[(size_t)row * KVD + (col - EMB)] = __float2bfloat16(v + bK[col - EMB]);
          } else {
            int d = col - EMB - KVD;
            oVt[(size_t)d * S_LEN + row] = __float2bfloat16(v + bV[d]);  // V^T direct
          }
        } else {
          oF[(size_t)row * EMB + col] = v + bF[col];
        }
      }
    }
  }
}

// ---------------- flash attention (causal, GQA) ----------------
// Balanced pairing: block i in [0,32) handles Q-tiles i and 63-i.
// 2-phase double-buffered K/V (T3 minimum recipe).
// Softmax: exp2-domain (log2e folded into Q scale), defer-max (T13, THR=8),
// per-lane partial l (single cross-lane reduce after the tile loop).

__device__ __forceinline__ void stage_kv(const __hip_bfloat16* __restrict__ Kb,
                                         const __hip_bfloat16* __restrict__ Vt,
                                         int kvh, int kv0, int wid,
                                         __hip_bfloat16* Ks, __hip_bfloat16* Vs) {
  const int lane = threadIdx.x & 63;
  #pragma unroll
  for (int call = 0; call < 4; ++call) {
    int ci = wid * 256 + call * 64 + lane;  // 16B chunk in [0,1024)
    int r = ci >> 4, sl = ci & 15;
    gl2lds16(Kb + (size_t)(kv0 + r) * KVD + kvh * HD + ((sl ^ (r & 7)) << 3),
             (char*)Ks + (wid * 256 + call * 64) * 16);
    int d = ci >> 3, vs = ci & 7;
    gl2lds16(Vt + (size_t)(kvh * HD + d) * S_LEN + kv0 + ((vs ^ (d & 7)) << 3),
             (char*)Vs + (wid * 256 + call * 64) * 16);
  }
}

__device__ __forceinline__ void attn_qtile(
    int qb, int h, int kvh, int wid, int g, int c,
    const __hip_bfloat16* __restrict__ Q, const __hip_bfloat16* __restrict__ Kb,
    const __hip_bfloat16* __restrict__ Vt, __hip_bfloat16* __restrict__ ctx,
    __hip_bfloat16 (*Ks)[64 * 128], __hip_bfloat16 (*Vs)[128 * 64],
    __hip_bfloat16* Pw) {
  const int qrow = qb * 64 + wid * 16 + c;
  short8 qf[4];
  #pragma unroll
  for (int ks = 0; ks < 4; ++ks)
    qf[ks] = *(const short8*)&Q[(size_t)qrow * EMB + h * HD + ks * 32 + g * 8];
  f32x4 o[8] = {};
  float mreg[4] = {-1e30f, -1e30f, -1e30f, -1e30f};
  float lreg[4] = {0.f, 0.f, 0.f, 0.f};  // per-lane PARTIAL row sums
  const int ntiles = qb + 1;
  stage_kv(Kb, Vt, kvh, 0, wid, Ks[0], Vs[0]);
  asm volatile("s_waitcnt vmcnt(0)" ::: "memory");
  __syncthreads();
  int buf = 0;
  for (int t = 0; t < ntiles; ++t) {
    const int kv0 = t * 64;
    if (t + 1 < ntiles)
      stage_kv(Kb, Vt, kvh, kv0 + 64, wid, Ks[buf ^ 1], Vs[buf ^ 1]);
    const char* Kbase = (const char*)Ks[buf];
    const char* Vbase = (const char*)Vs[buf];
    // S = Q * K^T  (16 q-rows x 64 kv), exp2 domain (scale pre-folded)
    f32x4 sc[4] = {};
    #pragma unroll
    for (int ks = 0; ks < 4; ++ks) {
      #pragma unroll
      for (int nt = 0; nt < 4; ++nt) {
        int kvr = nt * 16 + c;
        int byt = ((kvr << 8) + (ks << 6) + (g << 4)) ^ ((kvr & 7) << 4);
        short8 kf = *(const short8*)(Kbase + byt);
        sc[nt] = __builtin_amdgcn_mfma_f32_16x16x32_bf16(qf[ks], kf, sc[nt], 0, 0, 0);
      }
    }
    if (t == ntiles - 1) {  // diagonal tile: causal mask
      #pragma unroll
      for (int nt = 0; nt < 4; ++nt)
        #pragma unroll
        for (int r = 0; r < 4; ++r)
          if (kv0 + nt * 16 + c > qb * 64 + wid * 16 + g * 4 + r) sc[nt][r] = -1e30f;
    }
    // --- online softmax (defer-max + per-lane partial sum) ---
    float pmax[4];
    #pragma unroll
    for (int r = 0; r < 4; ++r)
      pmax[r] = fmaxf(fmaxf(sc[0][r], sc[1][r]), fmaxf(sc[2][r], sc[3][r]));
    bool ok = (pmax[0] <= mreg[0] + 8.f) & (pmax[1] <= mreg[1] + 8.f) &
              (pmax[2] <= mreg[2] + 8.f) & (pmax[3] <= mreg[3] + 8.f);
    if (!__all((int)ok)) {
      // rare path: grow the running max, rescale o and l
      float mx[4], corr[4];
      #pragma unroll
      for (int r = 0; r < 4; ++r) mx[r] = pmax[r];
      #pragma unroll
      for (int d = 1; d < 16; d <<= 1)
        #pragma unroll
        for (int r = 0; r < 4; ++r) mx[r] = fmaxf(mx[r], __shfl_xor(mx[r], d, 64));
      #pragma unroll
      for (int r = 0; r < 4; ++r) {
        float mn = fmaxf(mreg[r], mx[r]);
        corr[r] = fexp2(mreg[r] - mn);
        mreg[r] = mn;
        lreg[r] *= corr[r];
      }
      #pragma unroll
      for (int dt = 0; dt < 8; ++dt)
        #pragma unroll
        for (int r = 0; r < 4; ++r) o[dt][r] *= corr[r];
    }
    #pragma unroll
    for (int nt = 0; nt < 4; ++nt)
      #pragma unroll
      for (int r = 0; r < 4; ++r) sc[nt][r] = fexp2(sc[nt][r] - mreg[r]);
    #pragma unroll
    for (int r = 0; r < 4; ++r)
      lreg[r] += sc[0][r] + sc[1][r] + sc[2][r] + sc[3][r];
    // P -> per-wave LDS (C-frag -> A-frag relayout); intra-wave only, no barrier
    #pragma unroll
    for (int nt = 0; nt < 4; ++nt)
      #pragma unroll
      for (int r = 0; r < 4; ++r)
        Pw[(g * 4 + r) * 72 + nt * 16 + c] = __float2bfloat16(sc[nt][r]);
    // O += P * V
    #pragma unroll
    for (int k2 = 0; k2 < 2; ++k2) {
      short8 pf = *(const short8*)&Pw[c * 72 + k2 * 32 + g * 8];
      #pragma unroll
      for (int dt = 0; dt < 8; ++dt) {
        int d = dt * 16 + c;
        int byt = ((d << 7) + (k2 << 6) + (g << 4)) ^ ((d & 7) << 4);
        short8 vf = *(const short8*)(Vbase + byt);
        o[dt] = __builtin_amdgcn_mfma_f32_16x16x32_bf16(pf, vf, o[dt], 0, 0, 0);
      }
    }
    asm volatile("s_waitcnt vmcnt(0)" ::: "memory");
    __syncthreads();
    buf ^= 1;
  }
  // finalize: reduce partial l across the 16 c-lanes (once per q-tile)
  #pragma unroll
  for (int d = 1; d < 16; d <<= 1)
    #pragma unroll
    for (int r = 0; r < 4; ++r) lreg[r] += __shfl_xor(lreg[r], d, 64);
  float inv[4];
  #pragma unroll
  for (int r = 0; r < 4; ++r) inv[r] = 1.f / lreg[r];
  #pragma unroll
  for (int dt = 0; dt < 8; ++dt)
    #pragma unroll
    for (int r = 0; r < 4; ++r)
      ctx[(size_t)(qb * 64 + wid * 16 + g * 4 + r) * EMB + h * HD + dt * 16 + c] =
          __float2bfloat16(o[dt][r] * inv[r]);
}

__global__ __launch_bounds__(256, 2) void attn_kernel(
    const __hip_bfloat16* __restrict__ Q, const __hip_bfloat16* __restrict__ Kb,
    const __hip_bfloat16* __restrict__ Vt, __hip_bfloat16* __restrict__ ctx) {
  __shared__ __align__(16) __hip_bfloat16 Ks[2][64 * 128];   // [kv][d], XOR-swizzled
  __shared__ __align__(16) __hip_bfloat16 Vs[2][128 * 64];   // [d][kv], XOR-swizzled
  __shared__ __align__(16) __hip_bfloat16 Ps[4][16 * 72];    // per-wave P, stride 72
  const int h = blockIdx.y, i = blockIdx.x;
  const int kvh = h >> 2;
  const int wid = threadIdx.x >> 6, lane = threadIdx.x & 63;
  const int g = lane >> 4, c = lane & 15;
  attn_qtile(i, h, kvh, wid, g, c, Q, Kb, Vt, ctx, Ks, Vs, Ps[wid]);
  attn_qtile(63 - i, h, kvh, wid, g, c, Q, Kb, Vt, ctx, Ks, Vs, Ps[wid]);
}

extern "C" void kernel_launch(void* const* d_in, const int* in_sizes, int n_in,
                              void* d_out, int out_size, void* d_ws, size_t ws_size,
                              hipStream_t stream) {
  const float* x  = (const float*)d_in[0];
  // d_in[1] = causal mask (static, reimplemented in-kernel)
  const float* wq = (const float*)d_in[2];
  const float* qb = (const float*)d_in[3];
  const float* wk = (const float*)d_in[4];
  const float* kb = (const float*)d_in[5];
  const float* wv = (const float*)d_in[6];
  const float* vb = (const float*)d_in[7];
  const float* wo = (const float*)d_in[8];
  const float* ob = (const float*)d_in[9];

  char* ws = (char*)d_ws;
  __hip_bfloat16* x_bf  = (__hip_bfloat16*)(ws);              // 16 MB
  __hip_bfloat16* wqkvT = (__hip_bfloat16*)(ws + 16777216);   // 12 MB [3072][2048]
  __hip_bfloat16* woT   = (__hip_bfloat16*)(ws + 29360128);   // 8 MB  [2048][2048]
  __hip_bfloat16* q_bf  = (__hip_bfloat16*)(ws + 37748736);   // 16 MB [4096][2048]
  __hip_bfloat16* k_bf  = (__hip_bfloat16*)(ws + 54525952);   // 4 MB  [4096][512]
  __hip_bfloat16* vT    = (__hip_bfloat16*)(ws + 62914560);   // 4 MB  [512][4096]
  __hip_bfloat16* ctx   = (__hip_bfloat16*)(ws + 67108864);   // 16 MB [4096][2048]

  cvt_f32_bf16<<<2048, 256, 0, stream>>>(x, x_bf, S_LEN * EMB);
  transpose_weights<<<dim3(64, 64, 4), 256, 0, stream>>>(wq, wk, wv, wo, wqkvT, woT);

  gemm_bt<0><<<dim3(24, 32), 256, 0, stream>>>(x_bf, wqkvT, S_LEN, 3072, EMB,
      q_bf, k_bf, vT, qb, kb, vb, nullptr, nullptr);

  attn_kernel<<<dim3(32, NH), 256, 0, stream>>>(q_bf, k_bf, vT, ctx);

  gemm_bt<1><<<dim3(16, 32), 256, 0, stream>>>(ctx, woT, S_LEN, EMB, EMB,
      nullptr, nullptr, nullptr, nullptr, nullptr, nullptr, (float*)d_out, ob);
}